// Round 5
// baseline (297.578 us; speedup 1.0000x reference)
//
#include <hip/hip_runtime.h>

#define B_DIM 32
#define T_DIM 8192
#define C_DIM 32
#define N_ELEM (B_DIM * T_DIM * C_DIM)      /* 8388608 */
#define SUM_PT 16383
#define BITS_ELEM (B_DIM * SUM_PT * C_DIM)  /* 16776192 */
#define NLEVEL 14
#define PARTW 2048
#define QSCALE 0.17677669529663687f         /* 1/sqrt(32) */
#define ALPHA  70.710678118654755f          /* 4*INV_TEMP/sqrt(32) */

#define OWN 256                              /* rows (4096-res) owned per chunk block */
#define HALO 16                              /* exact-dependency halo (see analysis) */
#define MAXL (OWN + 2 * HALO)                /* 288 */

__device__ __forceinline__ float entf(float x) { return -(x * __logf(x + 1e-8f)); }
__device__ __forceinline__ float qval(float bit) { return bit * (2.0f * QSCALE) - QSCALE; }

// linear-interp (align_corners=False) of level-j quant at T-grid position t.
__device__ __forceinline__ float interp_q(const float* base, int ptj, int t) {
    const float a = (float)ptj * (1.0f / (float)T_DIM);
    float pos = ((float)t + 0.5f) * a - 0.5f;
    pos = fminf(fmaxf(pos, 0.0f), (float)(ptj - 1));
    const int lo = (int)pos;
    const int hi = min(lo + 1, ptj - 1);
    const float w = pos - (float)lo;
    return qval(base[(size_t)lo * C_DIM]) * (1.0f - w) + qval(base[(size_t)hi * C_DIM]) * w;
}

// pool_4096(up_T(q_j))[row] = mean of 2 interp samples.
__device__ __forceinline__ float delta_row4096(const float* base, int ptj, int r) {
    return 0.5f * (interp_q(base, ptj, 2 * r) + interp_q(base, ptj, 2 * r + 1));
}

// Closed-form sum over t in [m*64,(m+1)*64) of interp_q, for ptj <= 64.
__device__ float pooled_up_sum64(const float* base, int ptj, int m) {
    const int W = 64;
    const float a = (float)ptj * (1.0f / (float)T_DIM);
    const float p0 = ((float)(m * W) + 0.5f) * a - 0.5f;
    const float pmax = (float)(ptj - 1);
    float sum = 0.0f;
    int iL = 0;
    if (p0 < 0.0f) { iL = (int)ceilf(-p0 / a); if (iL > W) iL = W; }
    int iH = W - 1;
    if (p0 + (float)(W - 1) * a > pmax) {
        iH = (int)floorf((pmax - p0) / a);
        if (iH > W - 1) iH = W - 1;
        if (iH < -1) iH = -1;
    }
    if (iL > 0) sum += (float)iL * qval(base[0]);
    if (iH < W - 1) sum += (float)(W - 1 - iH) * qval(base[(size_t)(ptj - 1) * C_DIM]);
    if (iH >= iL) {
        const float pL = p0 + (float)iL * a;
        int l0 = (int)pL;
        if (l0 > ptj - 1) l0 = ptj - 1;
        const int is = (int)ceilf(((float)(l0 + 1) - p0) / a);
        const int endA = min(is - 1, iH);
        if (endA >= iL) {
            const int nA = endA - iL + 1;
            const float sI = 0.5f * (float)(iL + endA) * (float)nA;
            const float SA = (float)nA * (p0 - (float)l0) + a * sI;
            const float q0 = qval(base[(size_t)l0 * C_DIM]);
            const float q1 = qval(base[(size_t)min(l0 + 1, ptj - 1) * C_DIM]);
            sum += (float)nA * q0 + SA * (q1 - q0);
        }
        const int begB = max(is, iL);
        if (begB <= iH) {
            const int nB = iH - begB + 1;
            const float sI = 0.5f * (float)(begB + iH) * (float)nB;
            const float SB = (float)nB * (p0 - (float)(l0 + 1)) + a * sI;
            const float q1 = qval(base[(size_t)min(l0 + 1, ptj - 1) * C_DIM]);
            const float q2 = qval(base[(size_t)min(l0 + 2, ptj - 1) * C_DIM]);
            sum += (float)nB * q1 + SB * (q2 - q1);
        }
    }
    return sum;
}

// Per-block partial write: partial[level][comp][col]; entry barrier makes it reusable.
__device__ __forceinline__ void write_partials(float eAcc, float cAcc, float pAcc,
                                               float* partial, int level, int col) {
    __shared__ float sP[256];
    __shared__ float sEC[16];
    __syncthreads();
    const int grp = threadIdx.x >> 5, c = threadIdx.x & 31;
    float eg = eAcc, cg = cAcc;
#pragma unroll
    for (int m = 16; m >= 1; m >>= 1) { eg += __shfl_xor(eg, m, 32); cg += __shfl_xor(cg, m, 32); }
    if (c == 0) { sEC[grp * 2] = eg; sEC[grp * 2 + 1] = cg; }
    sP[threadIdx.x] = pAcc;
    __syncthreads();
    float* base = partial + (size_t)level * 34 * PARTW;
    if (threadIdx.x < 32) {
        float ps = 0.f;
#pragma unroll
        for (int r = 0; r < 8; ++r) ps += sP[threadIdx.x + r * 32];
        base[(size_t)(2 + threadIdx.x) * PARTW + col] = ps;
    }
    if (threadIdx.x == 0) {
        float se = 0.f, sc = 0.f;
#pragma unroll
        for (int g = 0; g < 8; ++g) { se += sEC[2 * g]; sc += sEC[2 * g + 1]; }
        base[0 * PARTW + col] = se;
        base[(size_t)1 * PARTW + col] = sc;
    }
}

// BSQ sign + loss accumulation (32-lane channel group).
__device__ __forceinline__ float bsq_eval(float v, float& bit, float& pA, float& eA, float& cA) {
    float sq = v * v;
#pragma unroll
    for (int m = 16; m >= 1; m >>= 1) sq += __shfl_xor(sq, m, 32);
    const float z = v / fmaxf(sqrtf(sq), 1e-12f);
    bit = (z > 0.f) ? 1.0f : 0.0f;
    const float zh = (z > 0.f) ? QSCALE : -QSCALE;
    const float d = zh - z;
    cA += d * d;
    const float p = 1.0f / (1.0f + __expf(ALPHA * z));
    pA += p;
    eA += entf(p) + entf(1.0f - p);
    return zh;
}

// ---------------------------------------------------------------------------
// initA: Racc[b,m,c] = 0.5*(f[b,2m,c]+f[b,2m+1,c])  (pool T -> 4096). float4.
// ---------------------------------------------------------------------------
__global__ void initA_kernel(const float* __restrict__ f, float* __restrict__ Racc) {
    const size_t o4 = (size_t)blockIdx.x * 256 + threadIdx.x;   // grid 4096
    const size_t o = o4 * 4;
    const int c = (int)(o & 31);
    const int m = (int)((o >> 5) & 4095);
    const int b = (int)(o >> 17);
    const size_t in = ((size_t)b * T_DIM + 2 * m) * C_DIM + c;
    const float4 r0 = *(const float4*)(f + in);
    const float4 r1 = *(const float4*)(f + in + C_DIM);
    float4 out;
    out.x = 0.5f * (r0.x + r1.x); out.y = 0.5f * (r0.y + r1.y);
    out.z = 0.5f * (r0.z + r1.z); out.w = 0.5f * (r0.w + r1.w);
    *(float4*)(Racc + o) = out;
}

// ---------------------------------------------------------------------------
// initB: F128[b,m,c] = mean of 32 Racc rows (pool 4096 -> 128).
// ---------------------------------------------------------------------------
__global__ void initB_kernel(const float* __restrict__ Racc, float* __restrict__ F128) {
    const int g = blockIdx.x * 8 + (threadIdx.x >> 5);          // grid 512
    const int c = threadIdx.x & 31;
    const int b = g >> 7, m = g & 127;
    const float* s = Racc + ((size_t)b * 4096 + m * 32) * C_DIM + c;
    float acc = 0.f;
#pragma unroll
    for (int r = 0; r < 32; ++r) acc += s[r * C_DIM];
    F128[((size_t)b * 128 + m) * C_DIM + c] = acc * (1.0f / 32.0f);
}

// ---------------------------------------------------------------------------
// Levels 0..7 fused: one block per b; P128 in LDS; closed-form corrections.
// ---------------------------------------------------------------------------
__global__ void fused_small_kernel(const float* __restrict__ F128, float* __restrict__ bits,
                                   float* __restrict__ partial) {
    const int b = blockIdx.x;
    __shared__ float P[128 * 32];
    __shared__ float qh[127 * 32];
    const int c = threadIdx.x & 31, grp = threadIdx.x >> 5;
    for (int i = threadIdx.x; i < 128 * 32; i += 256) P[i] = F128[(size_t)b * 128 * 32 + i];
    __syncthreads();
    for (int k = 0; k < 8; ++k) {
        const int pt = 1 << k, W2 = 128 >> k;
        float pAcc = 0.f, eAcc = 0.f, cAcc = 0.f;
        for (int o = grp; o < pt; o += 8) {
            float v = 0.f;
            for (int i = 0; i < W2; ++i) v += P[(o * W2 + i) * 32 + c];
            v *= (1.0f / (float)W2);
            float bit;
            bsq_eval(v, bit, pAcc, eAcc, cAcc);
            bits[((size_t)b * SUM_PT + (pt - 1) + o) * C_DIM + c] = bit;
            if (k < 7) qh[((pt - 1) + o) * 32 + c] = bit;
        }
        write_partials(eAcc, cAcc, pAcc, partial, k, b);
        if (k < 7) {
            __syncthreads();
            for (int m = grp; m < 128; m += 8)
                P[m * 32 + c] -= pooled_up_sum64(&qh[(pt - 1) * 32 + c], 1 << k, m) * (1.0f / 64.0f);
            __syncthreads();
        }
    }
}

// ---------------------------------------------------------------------------
// Levels 8..12 fused chunk kernel. Block owns rows [r0, r0+OWN) at 4096-res,
// loads +-HALO halo, applies j<=7 corrections from global bits, then runs
// pool -> BSQ -> correct for k=8..12 entirely in LDS (bits packed per-position
// as uint32 via ballot). Halo=16 proven sufficient for exactness at owned
// positions (corr-11 needs +-2 rows, corr-10 +-4, corr-9 +-8, bits-8 +-16).
// ---------------------------------------------------------------------------
__global__ __launch_bounds__(256) void chunk_kernel(const float* __restrict__ Racc,
                                                    float* __restrict__ bits,
                                                    float* __restrict__ partial) {
    const int b = blockIdx.x >> 4;           // 16 chunks per b
    const int chunk = blockIdx.x & 15;
    const int r0 = chunk * OWN, r1 = r0 + OWN;
    const int L0 = max(0, r0 - HALO);
    const int L1 = min(4096, r1 + HALO);
    const int nL = L1 - L0;
    __shared__ float Rl[MAXL * 32];
    __shared__ unsigned int bitsL[558];      // 18+36+72+144+288
    const int c = threadIdx.x & 31, grp = threadIdx.x >> 5;

    const float* gsrc = Racc + ((size_t)b * 4096 + L0) * C_DIM;
    for (int i = threadIdx.x * 4; i < nL * 32; i += 256 * 4)
        *(float4*)(Rl + i) = *(const float4*)(gsrc + i);
    __syncthreads();

    for (int rl = grp; rl < nL; rl += 8) {
        const int row = L0 + rl;
        float val = Rl[rl * 32 + c];
#pragma unroll
        for (int j = 0; j < 8; ++j) {
            const int ptj = 1 << j;
            val -= delta_row4096(bits + ((size_t)b * SUM_PT + (ptj - 1)) * C_DIM + c, ptj, row);
        }
        Rl[rl * 32 + c] = val;
    }
    __syncthreads();

    const int offs[5] = {0, 18, 54, 126, 270};
    for (int k = 8; k <= 12; ++k) {
        const int F = 4096 >> k;
        const int ptk = 1 << k;
        const int p0 = L0 / F, pN = nL / F;  // exact: L0,nL multiples of 16
        const int own0 = r0 / F, own1 = r1 / F;
        const int off = offs[k - 8];
        float pAcc = 0.f, eAcc = 0.f, cAcc = 0.f;
        for (int pl = grp; pl < pN; pl += 8) {
            float v = 0.f;
            for (int r = 0; r < F; ++r) v += Rl[(pl * F + r) * 32 + c];
            v *= (1.0f / (float)F);
            float sq = v * v;
#pragma unroll
            for (int m = 16; m >= 1; m >>= 1) sq += __shfl_xor(sq, m, 32);
            const float z = v / fmaxf(sqrtf(sq), 1e-12f);
            const unsigned long long bal = __ballot(z > 0.f);
            if (c == 0)
                bitsL[off + pl] = (threadIdx.x & 32) ? (unsigned)(bal >> 32) : (unsigned)bal;
            const int mg = p0 + pl;
            if (mg >= own0 && mg < own1) {
                bits[((size_t)b * SUM_PT + (ptk - 1) + mg) * C_DIM + c] = (z > 0.f) ? 1.f : 0.f;
                const float zh = (z > 0.f) ? QSCALE : -QSCALE;
                const float d = zh - z;
                cAcc += d * d;
                const float p = 1.0f / (1.0f + __expf(ALPHA * z));
                pAcc += p;
                eAcc += entf(p) + entf(1.0f - p);
            }
        }
        write_partials(eAcc, cAcc, pAcc, partial, k, blockIdx.x);  // entry+mid barriers
        __syncthreads();
        if (k < 12) {
            const float a = (float)ptk * (1.0f / (float)T_DIM);
            for (int rl = grp; rl < nL; rl += 8) {
                const int row = L0 + rl;
                float corr = 0.f;
#pragma unroll
                for (int s = 0; s < 2; ++s) {
                    float pos = ((float)(2 * row + s) + 0.5f) * a - 0.5f;
                    pos = fminf(fmaxf(pos, 0.0f), (float)(ptk - 1));
                    const int lo = (int)pos;
                    const int hi = min(lo + 1, ptk - 1);
                    const float w = pos - (float)lo;
                    const int lol = min(max(lo - p0, 0), pN - 1);   // clamp: only affects
                    const int hil = min(max(hi - p0, 0), pN - 1);   // don't-care halo rows
                    const float q0 = qval((float)((bitsL[off + lol] >> c) & 1u));
                    const float q1 = qval((float)((bitsL[off + hil] >> c) & 1u));
                    corr += q0 * (1.0f - w) + q1 * w;
                }
                Rl[rl * 32 + c] -= 0.5f * corr;
            }
            __syncthreads();
        }
    }
}

// ---------------------------------------------------------------------------
// Level 13: one block per (b, t-chunk of 512). Levels 0..6 bits preloaded in
// LDS; up = sum of 13 interps; out = up + zhat; bits13; loss partials.
// ---------------------------------------------------------------------------
__global__ __launch_bounds__(256) void final_kernel(const float* __restrict__ f,
                                                    float* __restrict__ outQ,
                                                    float* bits, float* __restrict__ partial) {
    const int b = blockIdx.x >> 4;           // grid 512
    const int sub = blockIdx.x & 15;
    __shared__ float qs[127 * 32];
    const int c = threadIdx.x & 31, grp = threadIdx.x >> 5;
    for (int i = threadIdx.x; i < 127 * 32; i += 256)
        qs[i] = bits[(size_t)b * SUM_PT * C_DIM + i];
    __syncthreads();
    float pAcc = 0.f, eAcc = 0.f, cAcc = 0.f;
    const int t0 = sub * 512;
    for (int tt = grp; tt < 512; tt += 8) {
        const int t = t0 + tt;
        float up = 0.f;
#pragma unroll
        for (int j = 0; j < 7; ++j) {        // LDS levels
            const int ptj = 1 << j;
            const float a = (float)ptj * (1.0f / (float)T_DIM);
            float pos = ((float)t + 0.5f) * a - 0.5f;
            pos = fminf(fmaxf(pos, 0.0f), (float)(ptj - 1));
            const int lo = (int)pos;
            const int hi = min(lo + 1, ptj - 1);
            const float w = pos - (float)lo;
            const float* bse = qs + ((ptj - 1)) * 32 + c;
            up += qval(bse[lo * 32]) * (1.0f - w) + qval(bse[hi * 32]) * w;
        }
#pragma unroll
        for (int j = 7; j < 13; ++j) {       // global levels
            const int ptj = 1 << j;
            up += interp_q(bits + ((size_t)b * SUM_PT + (ptj - 1)) * C_DIM + c, ptj, t);
        }
        const size_t idx = ((size_t)b * T_DIM + t) * C_DIM + c;
        const float v = f[idx] - up;
        float bit;
        const float zh = bsq_eval(v, bit, pAcc, eAcc, cAcc);
        bits[((size_t)b * SUM_PT + (T_DIM - 1) + t) * C_DIM + c] = bit;
        outQ[idx] = up + zh;
    }
    write_partials(eAcc, cAcc, pAcc, partial, 13, blockIdx.x);
}

// ---------------------------------------------------------------------------
__global__ void reduce_partials(const float* __restrict__ partial, float* __restrict__ acc) {
    const int level = blockIdx.x / 34;
    const int comp = blockIdx.x % 34;
    const int nblk = (level < 8) ? 32 : 512;
    const float* s = partial + ((size_t)level * 34 + comp) * PARTW;
    float v = 0.f;
    for (int i = threadIdx.x; i < nblk; i += 64) v += s[i];
#pragma unroll
    for (int m = 32; m >= 1; m >>= 1) v += __shfl_xor(v, m, 64);
    if (threadIdx.x == 0) acc[level * 64 + comp] = v;
}

__global__ void finalize_kernel(const float* __restrict__ acc, float* __restrict__ outL) {
    const int k = threadIdx.x >> 5;
    const int c = threadIdx.x & 31;
    if (k >= NLEVEL) return;
    const float cnt = (float)(B_DIM << k);
    const float avg_p = acc[k * 64 + 2 + c] / cnt;
    float ec = entf(avg_p) + entf(1.0f - avg_p);
#pragma unroll
    for (int m = 16; m >= 1; m >>= 1) ec += __shfl_xor(ec, m, 32);
    if (c == 0) {
        const float per_sample = acc[k * 64 + 0] / cnt;
        const float commit = acc[k * 64 + 1] / cnt;
        const float pen = (per_sample - ec) * (1.0f / 100.0f);
        outL[k] = pen * 0.1f + commit * 0.2f;
    }
}

extern "C" void kernel_launch(void* const* d_in, const int* in_sizes, int n_in,
                              void* d_out, int out_size, void* d_ws, size_t ws_size,
                              hipStream_t stream) {
    (void)in_sizes; (void)n_in; (void)out_size; (void)ws_size;
    const float* f = (const float*)d_in[0];
    float* outQ = (float*)d_out;                        // N_ELEM floats
    float* outBits = outQ + N_ELEM;                     // BITS_ELEM floats (0.0/1.0)
    float* outL = outBits + BITS_ELEM;                  // 14 floats
    float* Racc = outQ;                                 // pool-4096 residual in outQ region

    float* partial = (float*)d_ws;                      // 14*34*2048 floats (~3.9MB)
    float* acc = partial + (size_t)NLEVEL * 34 * PARTW; // 14*64 floats
    float* F128 = acc + NLEVEL * 64;                    // B*128*C floats (0.5MB)

    initA_kernel<<<4096, 256, 0, stream>>>(f, Racc);
    initB_kernel<<<512, 256, 0, stream>>>(Racc, F128);
    fused_small_kernel<<<B_DIM, 256, 0, stream>>>(F128, outBits, partial);
    chunk_kernel<<<512, 256, 0, stream>>>(Racc, outBits, partial);
    final_kernel<<<512, 256, 0, stream>>>(f, outQ, outBits, partial);
    reduce_partials<<<NLEVEL * 34, 64, 0, stream>>>(partial, acc);
    finalize_kernel<<<1, 512, 0, stream>>>(acc, outL);
}

// Round 6
// 246.769 us; speedup vs baseline: 1.2059x; 1.2059x over previous
//
#include <hip/hip_runtime.h>

#define B_DIM 32
#define T_DIM 8192
#define C_DIM 32
#define N_ELEM (B_DIM * T_DIM * C_DIM)      /* 8388608 */
#define SUM_PT 16383
#define BITS_ELEM (B_DIM * SUM_PT * C_DIM)  /* 16776192 */
#define NLEVEL 14
#define PARTW 2048
#define QSCALE 0.17677669529663687f         /* 1/sqrt(32) */
#define ALPHA  70.710678118654755f          /* 4*INV_TEMP/sqrt(32) */

#define OWN 128                              /* rows (4096-res) owned per chunk block */
#define HALO 16                              /* exact-dependency halo */
#define MAXL (OWN + 2 * HALO)                /* 160 */

__device__ __forceinline__ float entf(float x) { return -(x * __logf(x + 1e-8f)); }
__device__ __forceinline__ float qval(float bit) { return bit * (2.0f * QSCALE) - QSCALE; }

// interp of level-j quant at T-grid position t from packed sign words (bit c).
__device__ __forceinline__ float interp_pk(const unsigned int* __restrict__ pkbase,
                                           int ptj, int t, int c) {
    const float a = (float)ptj * (1.0f / (float)T_DIM);
    float pos = ((float)t + 0.5f) * a - 0.5f;
    pos = fminf(fmaxf(pos, 0.0f), (float)(ptj - 1));
    const int lo = (int)pos;
    const int hi = min(lo + 1, ptj - 1);
    const float w = pos - (float)lo;
    const float b0 = (float)((pkbase[lo] >> c) & 1u);
    const float b1 = (float)((pkbase[hi] >> c) & 1u);
    return ((b0 * (1.0f - w) + b1 * w) * 2.0f - 1.0f) * QSCALE;
}

// Closed-form sum over t in [m*64,(m+1)*64) of float-bits interp, ptj <= 64.
__device__ float pooled_up_sum64(const float* base, int ptj, int m) {
    const int W = 64;
    const float a = (float)ptj * (1.0f / (float)T_DIM);
    const float p0 = ((float)(m * W) + 0.5f) * a - 0.5f;
    const float pmax = (float)(ptj - 1);
    float sum = 0.0f;
    int iL = 0;
    if (p0 < 0.0f) { iL = (int)ceilf(-p0 / a); if (iL > W) iL = W; }
    int iH = W - 1;
    if (p0 + (float)(W - 1) * a > pmax) {
        iH = (int)floorf((pmax - p0) / a);
        if (iH > W - 1) iH = W - 1;
        if (iH < -1) iH = -1;
    }
    if (iL > 0) sum += (float)iL * qval(base[0]);
    if (iH < W - 1) sum += (float)(W - 1 - iH) * qval(base[(size_t)(ptj - 1) * C_DIM]);
    if (iH >= iL) {
        const float pL = p0 + (float)iL * a;
        int l0 = (int)pL;
        if (l0 > ptj - 1) l0 = ptj - 1;
        const int is = (int)ceilf(((float)(l0 + 1) - p0) / a);
        const int endA = min(is - 1, iH);
        if (endA >= iL) {
            const int nA = endA - iL + 1;
            const float sI = 0.5f * (float)(iL + endA) * (float)nA;
            const float SA = (float)nA * (p0 - (float)l0) + a * sI;
            const float q0 = qval(base[(size_t)l0 * C_DIM]);
            const float q1 = qval(base[(size_t)min(l0 + 1, ptj - 1) * C_DIM]);
            sum += (float)nA * q0 + SA * (q1 - q0);
        }
        const int begB = max(is, iL);
        if (begB <= iH) {
            const int nB = iH - begB + 1;
            const float sI = 0.5f * (float)(begB + iH) * (float)nB;
            const float SB = (float)nB * (p0 - (float)(l0 + 1)) + a * sI;
            const float q1 = qval(base[(size_t)min(l0 + 1, ptj - 1) * C_DIM]);
            const float q2 = qval(base[(size_t)min(l0 + 2, ptj - 1) * C_DIM]);
            sum += (float)nB * q1 + SB * (q2 - q1);
        }
    }
    return sum;
}

// Per-block partial write: partial[level][comp][col]; entry barrier -> reusable.
template <int NT>
__device__ __forceinline__ void write_partials(float eAcc, float cAcc, float pAcc,
                                               float* partial, int level, int col) {
    __shared__ float sP[NT];
    __shared__ float sEC[NT / 16];
    __syncthreads();
    const int grp = threadIdx.x >> 5, c = threadIdx.x & 31;
    float eg = eAcc, cg = cAcc;
#pragma unroll
    for (int m = 16; m >= 1; m >>= 1) { eg += __shfl_xor(eg, m, 32); cg += __shfl_xor(cg, m, 32); }
    if (c == 0) { sEC[grp * 2] = eg; sEC[grp * 2 + 1] = cg; }
    sP[threadIdx.x] = pAcc;
    __syncthreads();
    float* base = partial + (size_t)level * 34 * PARTW;
    if (threadIdx.x < 32) {
        float ps = 0.f;
#pragma unroll
        for (int r = 0; r < NT / 32; ++r) ps += sP[threadIdx.x + r * 32];
        base[(size_t)(2 + threadIdx.x) * PARTW + col] = ps;
    }
    if (threadIdx.x == 0) {
        float se = 0.f, sc = 0.f;
#pragma unroll
        for (int g = 0; g < NT / 32; ++g) { se += sEC[2 * g]; sc += sEC[2 * g + 1]; }
        base[0 * PARTW + col] = se;
        base[(size_t)1 * PARTW + col] = sc;
    }
}

// BSQ sign + loss accumulation (32-lane channel group).
__device__ __forceinline__ float bsq_eval(float v, float& bit, float& pA, float& eA, float& cA) {
    float sq = v * v;
#pragma unroll
    for (int m = 16; m >= 1; m >>= 1) sq += __shfl_xor(sq, m, 32);
    const float z = v / fmaxf(sqrtf(sq), 1e-12f);
    bit = (z > 0.f) ? 1.0f : 0.0f;
    const float zh = (z > 0.f) ? QSCALE : -QSCALE;
    const float d = zh - z;
    cA += d * d;
    const float p = 1.0f / (1.0f + __expf(ALPHA * z));
    pA += p;
    eA += entf(p) + entf(1.0f - p);
    return zh;
}

// ---------------------------------------------------------------------------
// init: block = (b, m of 128): pool 64 T-rows -> 32 Racc rows + 1 F128 row.
// ---------------------------------------------------------------------------
__global__ void init_kernel(const float* __restrict__ f, float* __restrict__ Racc,
                            float* __restrict__ F128) {
    const int b = blockIdx.x >> 7;
    const int m = blockIdx.x & 127;
    const int c = threadIdx.x & 31, grp = threadIdx.x >> 5;
    const float* fb = f + ((size_t)b * T_DIM + m * 64 + grp * 8) * C_DIM + c;
    float* rb = Racc + ((size_t)b * 4096 + m * 32 + grp * 4) * C_DIM + c;
    float s4 = 0.f;
#pragma unroll
    for (int i = 0; i < 4; ++i) {
        const float rv = 0.5f * (fb[(2 * i) * C_DIM] + fb[(2 * i + 1) * C_DIM]);
        rb[i * C_DIM] = rv;
        s4 += rv;
    }
    __shared__ float red[8][32];
    red[grp][c] = s4;
    __syncthreads();
    if (grp == 0) {
        float s = red[0][c] + red[1][c] + red[2][c] + red[3][c]
                + red[4][c] + red[5][c] + red[6][c] + red[7][c];
        F128[((size_t)b * 128 + m) * C_DIM + c] = s * (1.0f / 32.0f);
    }
}

// ---------------------------------------------------------------------------
// Levels 0..7: one 1024-thread block per b; P128 in LDS; closed-form corr.
// Writes float bits + packed words (levels 0..7 -> pk[b][0..254]).
// ---------------------------------------------------------------------------
__global__ __launch_bounds__(1024) void fused_small_kernel(const float* __restrict__ F128,
                                                           float* __restrict__ bits,
                                                           unsigned int* __restrict__ pkG,
                                                           float* __restrict__ partial) {
    const int b = blockIdx.x;
    __shared__ float P[128 * 32];
    __shared__ float qh[127 * 32];
    const int c = threadIdx.x & 31, grp = threadIdx.x >> 5;   // 32 groups
    for (int i = threadIdx.x; i < 128 * 32; i += 1024) P[i] = F128[(size_t)b * 128 * 32 + i];
    __syncthreads();
    for (int k = 0; k < 8; ++k) {
        const int pt = 1 << k, W2 = 128 >> k;
        float pAcc = 0.f, eAcc = 0.f, cAcc = 0.f;
        for (int o = grp; o < pt; o += 32) {
            float v = 0.f;
            for (int i = 0; i < W2; ++i) v += P[(o * W2 + i) * 32 + c];
            v *= (1.0f / (float)W2);
            float bit;
            bsq_eval(v, bit, pAcc, eAcc, cAcc);
            bits[((size_t)b * SUM_PT + (pt - 1) + o) * C_DIM + c] = bit;
            const unsigned long long bal = __ballot(bit > 0.5f);
            if (c == 0)
                pkG[(size_t)b * 8192 + (pt - 1) + o] =
                    (threadIdx.x & 32) ? (unsigned)(bal >> 32) : (unsigned)bal;
            if (k < 7) qh[((pt - 1) + o) * 32 + c] = bit;
        }
        write_partials<1024>(eAcc, cAcc, pAcc, partial, k, b);
        if (k < 7) {
            __syncthreads();
            for (int m = grp; m < 128; m += 32)
                P[m * 32 + c] -= pooled_up_sum64(&qh[(pt - 1) * 32 + c], 1 << k, m) * (1.0f / 64.0f);
            __syncthreads();
        }
    }
}

// ---------------------------------------------------------------------------
// Levels 8..12 chunk kernel: block owns 128 rows (+-16 halo) of Racc in LDS.
// j<=7 corrections from packed LDS bits; per-level pool->BSQ->correct in LDS.
// ---------------------------------------------------------------------------
__global__ __launch_bounds__(256) void chunk_kernel(const float* __restrict__ Racc,
                                                    float* __restrict__ bits,
                                                    unsigned int* __restrict__ pkG,
                                                    float* __restrict__ partial) {
    const int b = blockIdx.x >> 5;           // 32 chunks per b
    const int chunk = blockIdx.x & 31;
    const int r0 = chunk * OWN, r1 = r0 + OWN;
    const int L0 = max(0, r0 - HALO);
    const int L1 = min(4096, r1 + HALO);
    const int nL = L1 - L0;
    __shared__ float Rl[MAXL * 32];
    __shared__ unsigned int bitsL[310];      // 10+20+40+80+160
    __shared__ unsigned int pk07[255];
    const int c = threadIdx.x & 31, grp = threadIdx.x >> 5;

    const float* gsrc = Racc + ((size_t)b * 4096 + L0) * C_DIM;
    for (int i = threadIdx.x * 4; i < nL * 32; i += 256 * 4)
        *(float4*)(Rl + i) = *(const float4*)(gsrc + i);
    for (int i = threadIdx.x; i < 255; i += 256) pk07[i] = pkG[(size_t)b * 8192 + i];
    __syncthreads();

    for (int rl = grp; rl < nL; rl += 8) {
        const int row = L0 + rl;
        float val = Rl[rl * 32 + c];
#pragma unroll
        for (int j = 0; j < 8; ++j) {
            const int ptj = 1 << j;
            val -= 0.5f * (interp_pk(pk07 + (ptj - 1), ptj, 2 * row, c) +
                           interp_pk(pk07 + (ptj - 1), ptj, 2 * row + 1, c));
        }
        Rl[rl * 32 + c] = val;
    }
    __syncthreads();

    const int offs[5] = {0, 10, 30, 70, 150};
    for (int k = 8; k <= 12; ++k) {
        const int F = 4096 >> k;
        const int ptk = 1 << k;
        const int p0 = L0 / F, pN = nL / F;  // L0, nL multiples of 16
        const int own0 = r0 / F, own1 = r1 / F;
        const int off = offs[k - 8];
        float pAcc = 0.f, eAcc = 0.f, cAcc = 0.f;
        for (int pl = grp; pl < pN; pl += 8) {
            float v = 0.f;
            for (int r = 0; r < F; ++r) v += Rl[(pl * F + r) * 32 + c];
            v *= (1.0f / (float)F);
            float sq = v * v;
#pragma unroll
            for (int m = 16; m >= 1; m >>= 1) sq += __shfl_xor(sq, m, 32);
            const float z = v / fmaxf(sqrtf(sq), 1e-12f);
            const unsigned long long bal = __ballot(z > 0.f);
            const unsigned int word = (threadIdx.x & 32) ? (unsigned)(bal >> 32) : (unsigned)bal;
            if (c == 0) bitsL[off + pl] = word;
            const int mg = p0 + pl;
            if (mg >= own0 && mg < own1) {
                bits[((size_t)b * SUM_PT + (ptk - 1) + mg) * C_DIM + c] = (z > 0.f) ? 1.f : 0.f;
                if (c == 0) pkG[(size_t)b * 8192 + (ptk - 1) + mg] = word;
                const float zh = (z > 0.f) ? QSCALE : -QSCALE;
                const float d = zh - z;
                cAcc += d * d;
                const float p = 1.0f / (1.0f + __expf(ALPHA * z));
                pAcc += p;
                eAcc += entf(p) + entf(1.0f - p);
            }
        }
        write_partials<256>(eAcc, cAcc, pAcc, partial, k, blockIdx.x);
        __syncthreads();
        if (k < 12) {
            const float a = (float)ptk * (1.0f / (float)T_DIM);
            for (int rl = grp; rl < nL; rl += 8) {
                const int row = L0 + rl;
                float corr = 0.f;
#pragma unroll
                for (int s = 0; s < 2; ++s) {
                    float pos = ((float)(2 * row + s) + 0.5f) * a - 0.5f;
                    pos = fminf(fmaxf(pos, 0.0f), (float)(ptk - 1));
                    const int lo = (int)pos;
                    const int hi = min(lo + 1, ptk - 1);
                    const float w = pos - (float)lo;
                    const int lol = min(max(lo - p0, 0), pN - 1);   // clamp only hits
                    const int hil = min(max(hi - p0, 0), pN - 1);   // don't-care halo rows
                    const float q0 = qval((float)((bitsL[off + lol] >> c) & 1u));
                    const float q1 = qval((float)((bitsL[off + hil] >> c) & 1u));
                    corr += q0 * (1.0f - w) + q1 * w;
                }
                Rl[rl * 32 + c] -= 0.5f * corr;
            }
            __syncthreads();
        }
    }
}

// ---------------------------------------------------------------------------
// Level 13: block = (b, 256-t chunk). ALL levels' packed bits (8191 words) in
// LDS; up = 13 LDS interps; out = up + zhat; bits13 float; loss partials.
// ---------------------------------------------------------------------------
__global__ __launch_bounds__(256) void final_kernel(const float* __restrict__ f,
                                                    float* __restrict__ outQ,
                                                    float* __restrict__ bits,
                                                    const unsigned int* __restrict__ pkG,
                                                    float* __restrict__ partial) {
    const int b = blockIdx.x >> 5;           // grid 1024
    const int sub = blockIdx.x & 31;
    __shared__ unsigned int pkAll[8191];
    const int c = threadIdx.x & 31, grp = threadIdx.x >> 5;
    for (int i = threadIdx.x; i < 8191; i += 256) pkAll[i] = pkG[(size_t)b * 8192 + i];
    __syncthreads();
    float pAcc = 0.f, eAcc = 0.f, cAcc = 0.f;
    const int t0 = sub * 256;
    for (int tt = grp; tt < 256; tt += 8) {
        const int t = t0 + tt;
        float up = 0.f;
#pragma unroll
        for (int j = 0; j < 13; ++j) {
            const int ptj = 1 << j;
            up += interp_pk(pkAll + (ptj - 1), ptj, t, c);
        }
        const size_t idx = ((size_t)b * T_DIM + t) * C_DIM + c;
        const float v = f[idx] - up;
        float bit;
        const float zh = bsq_eval(v, bit, pAcc, eAcc, cAcc);
        bits[((size_t)b * SUM_PT + (T_DIM - 1) + t) * C_DIM + c] = bit;
        outQ[idx] = up + zh;
    }
    write_partials<256>(eAcc, cAcc, pAcc, partial, 13, blockIdx.x);
}

// ---------------------------------------------------------------------------
__global__ void reduce_partials(const float* __restrict__ partial, float* __restrict__ acc) {
    const int level = blockIdx.x / 34;
    const int comp = blockIdx.x % 34;
    const int nblk = (level < 8) ? 32 : 1024;
    const float* s = partial + ((size_t)level * 34 + comp) * PARTW;
    float v = 0.f;
    for (int i = threadIdx.x; i < nblk; i += 64) v += s[i];
#pragma unroll
    for (int m = 32; m >= 1; m >>= 1) v += __shfl_xor(v, m, 64);
    if (threadIdx.x == 0) acc[level * 64 + comp] = v;
}

__global__ void finalize_kernel(const float* __restrict__ acc, float* __restrict__ outL) {
    const int k = threadIdx.x >> 5;
    const int c = threadIdx.x & 31;
    if (k >= NLEVEL) return;
    const float cnt = (float)(B_DIM << k);
    const float avg_p = acc[k * 64 + 2 + c] / cnt;
    float ec = entf(avg_p) + entf(1.0f - avg_p);
#pragma unroll
    for (int m = 16; m >= 1; m >>= 1) ec += __shfl_xor(ec, m, 32);
    if (c == 0) {
        const float per_sample = acc[k * 64 + 0] / cnt;
        const float commit = acc[k * 64 + 1] / cnt;
        const float pen = (per_sample - ec) * (1.0f / 100.0f);
        outL[k] = pen * 0.1f + commit * 0.2f;
    }
}

extern "C" void kernel_launch(void* const* d_in, const int* in_sizes, int n_in,
                              void* d_out, int out_size, void* d_ws, size_t ws_size,
                              hipStream_t stream) {
    (void)in_sizes; (void)n_in; (void)out_size; (void)ws_size;
    const float* f = (const float*)d_in[0];
    float* outQ = (float*)d_out;                        // N_ELEM floats
    float* outBits = outQ + N_ELEM;                     // BITS_ELEM floats (0.0/1.0)
    float* outL = outBits + BITS_ELEM;                  // 14 floats
    float* Racc = outQ;                                 // pool-4096 residual in outQ region

    float* partial = (float*)d_ws;                      // 14*34*2048 floats (~3.9MB)
    float* acc = partial + (size_t)NLEVEL * 34 * PARTW; // 14*64 floats
    float* F128 = acc + NLEVEL * 64;                    // B*128*C floats (0.5MB)
    unsigned int* pkG = (unsigned int*)(F128 + (size_t)B_DIM * 128 * C_DIM); // B*8192 words

    init_kernel<<<B_DIM * 128, 256, 0, stream>>>(f, Racc, F128);
    fused_small_kernel<<<B_DIM, 1024, 0, stream>>>(F128, outBits, pkG, partial);
    chunk_kernel<<<B_DIM * 32, 256, 0, stream>>>(Racc, outBits, pkG, partial);
    final_kernel<<<B_DIM * 32, 256, 0, stream>>>(f, outQ, outBits, pkG, partial);
    reduce_partials<<<NLEVEL * 34, 64, 0, stream>>>(partial, acc);
    finalize_kernel<<<1, 512, 0, stream>>>(acc, outL);
}

// Round 7
// 172.214 us; speedup vs baseline: 1.7280x; 1.4329x over previous
//
#include <hip/hip_runtime.h>

#define B_DIM 32
#define T_DIM 8192
#define C_DIM 32
#define N_ELEM (B_DIM * T_DIM * C_DIM)      /* 8388608 */
#define SUM_PT 16383
#define BITS_ELEM (B_DIM * SUM_PT * C_DIM)  /* 16776192 */
#define NLEVEL 14
#define PARTW 2048
#define QSCALE 0.17677669529663687f         /* 1/sqrt(32) */
#define ALPHA  70.710678118654755f          /* 4*INV_TEMP/sqrt(32) */

#define OWN 128                              /* 4096-res rows owned per chunk block */
#define HALO 16
#define MAXL (OWN + 2 * HALO)                /* 160 */

__device__ __forceinline__ float entf(float x) { return -(x * __logf(x + 1e-8f)); }
__device__ __forceinline__ float qval(float bit) { return bit * (2.0f * QSCALE) - QSCALE; }

// interp of level-j quant at (possibly half-integer) T-position tpos, packed bit c.
__device__ __forceinline__ float interp_pk(const unsigned int* __restrict__ pkbase,
                                           int ptj, float tpos, int c) {
    const float a = (float)ptj * (1.0f / (float)T_DIM);
    float pos = (tpos + 0.5f) * a - 0.5f;
    pos = fminf(fmaxf(pos, 0.0f), (float)(ptj - 1));
    const int lo = (int)pos;
    const int hi = min(lo + 1, ptj - 1);
    const float w = pos - (float)lo;
    const float b0 = (float)((pkbase[lo] >> c) & 1u);
    const float b1 = (float)((pkbase[hi] >> c) & 1u);
    return ((b0 * (1.0f - w) + b1 * w) * 2.0f - 1.0f) * QSCALE;
}

// pooled-to-4096 correction of level k via midpoint identity, local packed window.
__device__ __forceinline__ float corr_mid_local(const unsigned int* __restrict__ bl,
                                                int ptk, int row, int c, int p0, int pN) {
    const float a = (float)ptk * (1.0f / (float)T_DIM);
    float pos = (float)(2 * row + 1) * a - 0.5f;
    pos = fminf(fmaxf(pos, 0.0f), (float)(ptk - 1));
    const int lo = (int)pos;
    const int hi = min(lo + 1, ptk - 1);
    const float w = pos - (float)lo;
    const int lol = min(max(lo - p0, 0), pN - 1);   // clamp only hits don't-care halo
    const int hil = min(max(hi - p0, 0), pN - 1);
    const float b0 = (float)((bl[lol] >> c) & 1u);
    const float b1 = (float)((bl[hil] >> c) & 1u);
    return ((b0 * (1.0f - w) + b1 * w) * 2.0f - 1.0f) * QSCALE;
}

// Closed-form sum over t in [m*64,(m+1)*64) of float-bits interp, ptj <= 64.
__device__ float pooled_up_sum64(const float* base, int ptj, int m) {
    const int W = 64;
    const float a = (float)ptj * (1.0f / (float)T_DIM);
    const float p0 = ((float)(m * W) + 0.5f) * a - 0.5f;
    const float pmax = (float)(ptj - 1);
    float sum = 0.0f;
    int iL = 0;
    if (p0 < 0.0f) { iL = (int)ceilf(-p0 / a); if (iL > W) iL = W; }
    int iH = W - 1;
    if (p0 + (float)(W - 1) * a > pmax) {
        iH = (int)floorf((pmax - p0) / a);
        if (iH > W - 1) iH = W - 1;
        if (iH < -1) iH = -1;
    }
    if (iL > 0) sum += (float)iL * qval(base[0]);
    if (iH < W - 1) sum += (float)(W - 1 - iH) * qval(base[(size_t)(ptj - 1) * C_DIM]);
    if (iH >= iL) {
        const float pL = p0 + (float)iL * a;
        int l0 = (int)pL;
        if (l0 > ptj - 1) l0 = ptj - 1;
        const int is = (int)ceilf(((float)(l0 + 1) - p0) / a);
        const int endA = min(is - 1, iH);
        if (endA >= iL) {
            const int nA = endA - iL + 1;
            const float sI = 0.5f * (float)(iL + endA) * (float)nA;
            const float SA = (float)nA * (p0 - (float)l0) + a * sI;
            const float q0 = qval(base[(size_t)l0 * C_DIM]);
            const float q1 = qval(base[(size_t)min(l0 + 1, ptj - 1) * C_DIM]);
            sum += (float)nA * q0 + SA * (q1 - q0);
        }
        const int begB = max(is, iL);
        if (begB <= iH) {
            const int nB = iH - begB + 1;
            const float sI = 0.5f * (float)(begB + iH) * (float)nB;
            const float SB = (float)nB * (p0 - (float)(l0 + 1)) + a * sI;
            const float q1 = qval(base[(size_t)min(l0 + 1, ptj - 1) * C_DIM]);
            const float q2 = qval(base[(size_t)min(l0 + 2, ptj - 1) * C_DIM]);
            sum += (float)nB * q1 + SB * (q2 - q1);
        }
    }
    return sum;
}

template <int NT>
__device__ __forceinline__ void write_partials(float eAcc, float cAcc, float pAcc,
                                               float* partial, int level, int col) {
    __shared__ float sP[NT];
    __shared__ float sEC[NT / 16];
    __syncthreads();
    const int grp = threadIdx.x >> 5, c = threadIdx.x & 31;
    float eg = eAcc, cg = cAcc;
#pragma unroll
    for (int m = 16; m >= 1; m >>= 1) { eg += __shfl_xor(eg, m, 32); cg += __shfl_xor(cg, m, 32); }
    if (c == 0) { sEC[grp * 2] = eg; sEC[grp * 2 + 1] = cg; }
    sP[threadIdx.x] = pAcc;
    __syncthreads();
    float* base = partial + (size_t)level * 34 * PARTW;
    if (threadIdx.x < 32) {
        float ps = 0.f;
#pragma unroll
        for (int r = 0; r < NT / 32; ++r) ps += sP[threadIdx.x + r * 32];
        base[(size_t)(2 + threadIdx.x) * PARTW + col] = ps;
    }
    if (threadIdx.x == 0) {
        float se = 0.f, sc = 0.f;
#pragma unroll
        for (int g = 0; g < NT / 32; ++g) { se += sEC[2 * g]; sc += sEC[2 * g + 1]; }
        base[0 * PARTW + col] = se;
        base[(size_t)1 * PARTW + col] = sc;
    }
}

__device__ __forceinline__ float bsq_eval(float v, float& bit, float& pA, float& eA, float& cA) {
    float sq = v * v;
#pragma unroll
    for (int m = 16; m >= 1; m >>= 1) sq += __shfl_xor(sq, m, 32);
    const float z = v / fmaxf(sqrtf(sq), 1e-12f);
    bit = (z > 0.f) ? 1.0f : 0.0f;
    const float zh = (z > 0.f) ? QSCALE : -QSCALE;
    const float d = zh - z;
    cA += d * d;
    const float p = 1.0f / (1.0f + __expf(ALPHA * z));
    pA += p;
    eA += entf(p) + entf(1.0f - p);
    return zh;
}

// ---------------------------------------------------------------------------
// init: F128[b,m,c] = mean of 64 f rows. Grid B*128.
// ---------------------------------------------------------------------------
__global__ void init_kernel(const float* __restrict__ f, float* __restrict__ F128) {
    const int b = blockIdx.x >> 7, m = blockIdx.x & 127;
    const int c = threadIdx.x & 31, grp = threadIdx.x >> 5;
    const float* fb = f + ((size_t)b * T_DIM + m * 64 + grp * 8) * C_DIM + c;
    float s = 0.f;
#pragma unroll
    for (int i = 0; i < 8; ++i) s += fb[i * C_DIM];
    __shared__ float red[8][32];
    red[grp][c] = s;
    __syncthreads();
    if (grp == 0) {
        float t = red[0][c] + red[1][c] + red[2][c] + red[3][c]
                + red[4][c] + red[5][c] + red[6][c] + red[7][c];
        F128[((size_t)b * 128 + m) * C_DIM + c] = t * (1.0f / 64.0f);
    }
}

// ---------------------------------------------------------------------------
// Levels 0..7: one 1024-thread block per b; P128 in LDS; closed-form corr.
// ---------------------------------------------------------------------------
__global__ __launch_bounds__(1024) void fused_small_kernel(const float* __restrict__ F128,
                                                           float* __restrict__ bits,
                                                           unsigned int* __restrict__ pkG,
                                                           float* __restrict__ partial) {
    const int b = blockIdx.x;
    __shared__ float P[128 * 32];
    __shared__ float qh[127 * 32];
    const int c = threadIdx.x & 31, grp = threadIdx.x >> 5;
    for (int i = threadIdx.x; i < 128 * 32; i += 1024) P[i] = F128[(size_t)b * 128 * 32 + i];
    __syncthreads();
    for (int k = 0; k < 8; ++k) {
        const int pt = 1 << k, W2 = 128 >> k;
        float pAcc = 0.f, eAcc = 0.f, cAcc = 0.f;
        for (int o = grp; o < pt; o += 32) {
            float v = 0.f;
            for (int i = 0; i < W2; ++i) v += P[(o * W2 + i) * 32 + c];
            v *= (1.0f / (float)W2);
            float bit;
            bsq_eval(v, bit, pAcc, eAcc, cAcc);
            bits[((size_t)b * SUM_PT + (pt - 1) + o) * C_DIM + c] = bit;
            const unsigned long long bal = __ballot(bit > 0.5f);
            if (c == 0)
                pkG[(size_t)b * 8192 + (pt - 1) + o] =
                    (threadIdx.x & 32) ? (unsigned)(bal >> 32) : (unsigned)bal;
            if (k < 7) qh[((pt - 1) + o) * 32 + c] = bit;
        }
        write_partials<1024>(eAcc, cAcc, pAcc, partial, k, b);
        if (k < 7) {
            __syncthreads();
            for (int m = grp; m < 128; m += 32)
                P[m * 32 + c] -= pooled_up_sum64(&qh[(pt - 1) * 32 + c], 1 << k, m) * (1.0f / 64.0f);
            __syncthreads();
        }
    }
}

// ---------------------------------------------------------------------------
// Levels 8..12 chunk: pool f 2:1 on load; segment-linear j<=7 correction
// (16-row segments, 2 evals each); per-level pool->BSQ->mid-interp correct.
// ---------------------------------------------------------------------------
__global__ __launch_bounds__(256) void chunk_kernel(const float* __restrict__ f,
                                                    float* __restrict__ bits,
                                                    unsigned int* __restrict__ pkG,
                                                    float* __restrict__ partial) {
    const int b = blockIdx.x >> 5;
    const int chunk = blockIdx.x & 31;
    const int r0 = chunk * OWN, r1 = r0 + OWN;
    const int L0 = max(0, r0 - HALO);
    const int L1 = min(4096, r1 + HALO);
    const int nL = L1 - L0;
    const int nSeg = nL >> 4;
    __shared__ float Rl[MAXL * 32];
    __shared__ unsigned int bitsL[310];
    __shared__ unsigned int pk07[255];
    __shared__ float segA[10][32], segB[10][32];
    const int c = threadIdx.x & 31, grp = threadIdx.x >> 5;

    const float* fb = f + ((size_t)b * T_DIM + (size_t)L0 * 2) * C_DIM;
    for (int i = threadIdx.x; i < nL * 8; i += 256) {
        const int row = i >> 3, c4 = i & 7;
        const float4 v0 = *(const float4*)(fb + (size_t)(2 * row) * 32 + c4 * 4);
        const float4 v1 = *(const float4*)(fb + (size_t)(2 * row + 1) * 32 + c4 * 4);
        float4 o;
        o.x = 0.5f * (v0.x + v1.x); o.y = 0.5f * (v0.y + v1.y);
        o.z = 0.5f * (v0.z + v1.z); o.w = 0.5f * (v0.w + v1.w);
        *(float4*)(Rl + row * 32 + c4 * 4) = o;
    }
    for (int i = threadIdx.x; i < 255; i += 256) pk07[i] = pkG[(size_t)b * 8192 + i];
    __syncthreads();

    // j<=7 batch correction: 2 mid-evals per 16-row segment, linear apply.
    for (int w = threadIdx.x; w < nSeg * 32; w += 256) {
        const int s = w >> 5, cc = w & 31;
        const int rg = L0 + s * 16;
        float c0 = 0.f, c1 = 0.f;
#pragma unroll
        for (int j = 0; j < 8; ++j) {
            const int ptj = 1 << j;
            c0 += interp_pk(pk07 + (ptj - 1), ptj, (float)(2 * rg) + 0.5f, cc);
            c1 += interp_pk(pk07 + (ptj - 1), ptj, (float)(2 * rg + 2) + 0.5f, cc);
        }
        segA[s][cc] = c0;
        segB[s][cc] = c1 - c0;
    }
    __syncthreads();
    for (int rl = grp; rl < nL; rl += 8) {
        const int s = rl >> 4;
        Rl[rl * 32 + c] -= fmaf((float)(rl & 15), segB[s][c], segA[s][c]);
    }
    __syncthreads();

    const int offs[5] = {0, 10, 30, 70, 150};
    for (int k = 8; k <= 12; ++k) {
        const int F = 4096 >> k;
        const int ptk = 1 << k;
        const int p0 = L0 / F, pN = nL / F;
        const int own0 = r0 / F, own1 = r1 / F;
        const int off = offs[k - 8];
        float pAcc = 0.f, eAcc = 0.f, cAcc = 0.f;
        for (int pl = grp; pl < pN; pl += 8) {
            float v = 0.f;
            for (int r = 0; r < F; ++r) v += Rl[(pl * F + r) * 32 + c];
            v *= (1.0f / (float)F);
            float sq = v * v;
#pragma unroll
            for (int m = 16; m >= 1; m >>= 1) sq += __shfl_xor(sq, m, 32);
            const float z = v / fmaxf(sqrtf(sq), 1e-12f);
            const unsigned long long bal = __ballot(z > 0.f);
            const unsigned int word = (threadIdx.x & 32) ? (unsigned)(bal >> 32) : (unsigned)bal;
            if (c == 0) bitsL[off + pl] = word;
            const int mg = p0 + pl;
            if (mg >= own0 && mg < own1) {
                bits[((size_t)b * SUM_PT + (ptk - 1) + mg) * C_DIM + c] = (z > 0.f) ? 1.f : 0.f;
                if (c == 0) pkG[(size_t)b * 8192 + (ptk - 1) + mg] = word;
                const float zh = (z > 0.f) ? QSCALE : -QSCALE;
                const float d = zh - z;
                cAcc += d * d;
                const float p = 1.0f / (1.0f + __expf(ALPHA * z));
                pAcc += p;
                eAcc += entf(p) + entf(1.0f - p);
            }
        }
        write_partials<256>(eAcc, cAcc, pAcc, partial, k, blockIdx.x);
        __syncthreads();
        if (k < 12) {
            for (int rl = grp; rl < nL; rl += 8)
                Rl[rl * 32 + c] -= corr_mid_local(bitsL + off, ptk, L0 + rl, c, p0, pN);
            __syncthreads();
        }
    }
}

// ---------------------------------------------------------------------------
// Level 13: segment-linear j<=8 (16-t segments) + direct j=9..12 from
// windowed packed bits; out = up + zhat; bits13; loss partials.
// ---------------------------------------------------------------------------
__global__ __launch_bounds__(256) void final_kernel(const float* __restrict__ f,
                                                    float* __restrict__ outQ,
                                                    float* __restrict__ bits,
                                                    const unsigned int* __restrict__ pkG,
                                                    float* __restrict__ partial) {
    const int b = blockIdx.x >> 5;
    const int sub = blockIdx.x & 31;
    const int t0 = sub * 256;
    __shared__ unsigned int pkW[764];
    __shared__ float segA[16][32], segB[16][32];
    const int c = threadIdx.x & 31, grp = threadIdx.x >> 5;
    const unsigned int* pgb = pkG + (size_t)b * 8192;
    for (int i = threadIdx.x; i < 511; i += 256) pkW[i] = pgb[i];
    int woff[4], wbase[4];
    int o = 511;
#pragma unroll
    for (int j = 9; j <= 12; ++j) {
        const int ptj = 1 << j;
        const int w0 = max(0, ((t0 * ptj) >> 13) - 1);
        const int w1 = min(ptj - 1, (((t0 + 256) * ptj) >> 13) + 1);
        const int cnt = w1 - w0 + 1;
        for (int i = threadIdx.x; i < cnt; i += 256) pkW[o + i] = pgb[(ptj - 1) + w0 + i];
        woff[j - 9] = o;
        wbase[j - 9] = w0;
        o += cnt;
    }
    __syncthreads();
    for (int w = threadIdx.x; w < 512; w += 256) {
        const int s = w >> 5, cc = w & 31;
        const int tA = t0 + s * 16;
        float c0 = 0.f, c1 = 0.f;
#pragma unroll
        for (int j = 0; j <= 8; ++j) {
            const int ptj = 1 << j;
            c0 += interp_pk(pkW + (ptj - 1), ptj, (float)tA, cc);
            c1 += interp_pk(pkW + (ptj - 1), ptj, (float)(tA + 1), cc);
        }
        segA[s][cc] = c0;
        segB[s][cc] = c1 - c0;
    }
    __syncthreads();
    float pAcc = 0.f, eAcc = 0.f, cAcc = 0.f;
    for (int tt = grp; tt < 256; tt += 8) {
        const int t = t0 + tt;
        float up = fmaf((float)(tt & 15), segB[tt >> 4][c], segA[tt >> 4][c]);
#pragma unroll
        for (int j = 9; j <= 12; ++j) {
            const int ptj = 1 << j;
            const float a = (float)ptj * (1.0f / (float)T_DIM);
            float pos = ((float)t + 0.5f) * a - 0.5f;
            pos = fminf(fmaxf(pos, 0.0f), (float)(ptj - 1));
            const int lo = (int)pos;
            const int hi = min(lo + 1, ptj - 1);
            const float w = pos - (float)lo;
            const unsigned int* base = pkW + (woff[j - 9] - wbase[j - 9]);
            const float b0 = (float)((base[lo] >> c) & 1u);
            const float b1 = (float)((base[hi] >> c) & 1u);
            up += ((b0 * (1.0f - w) + b1 * w) * 2.0f - 1.0f) * QSCALE;
        }
        const size_t idx = ((size_t)b * T_DIM + t) * C_DIM + c;
        const float v = f[idx] - up;
        float bit;
        const float zh = bsq_eval(v, bit, pAcc, eAcc, cAcc);
        bits[((size_t)b * SUM_PT + (T_DIM - 1) + t) * C_DIM + c] = bit;
        outQ[idx] = up + zh;
    }
    write_partials<256>(eAcc, cAcc, pAcc, partial, 13, blockIdx.x);
}

// ---------------------------------------------------------------------------
__global__ void reduce_partials(const float* __restrict__ partial, float* __restrict__ acc) {
    const int level = blockIdx.x / 34;
    const int comp = blockIdx.x % 34;
    const int nblk = (level < 8) ? 32 : 1024;
    const float* s = partial + ((size_t)level * 34 + comp) * PARTW;
    float v = 0.f;
    for (int i = threadIdx.x; i < nblk; i += 64) v += s[i];
#pragma unroll
    for (int m = 32; m >= 1; m >>= 1) v += __shfl_xor(v, m, 64);
    if (threadIdx.x == 0) acc[level * 64 + comp] = v;
}

__global__ void finalize_kernel(const float* __restrict__ acc, float* __restrict__ outL) {
    const int k = threadIdx.x >> 5;
    const int c = threadIdx.x & 31;
    if (k >= NLEVEL) return;
    const float cnt = (float)(B_DIM << k);
    const float avg_p = acc[k * 64 + 2 + c] / cnt;
    float ec = entf(avg_p) + entf(1.0f - avg_p);
#pragma unroll
    for (int m = 16; m >= 1; m >>= 1) ec += __shfl_xor(ec, m, 32);
    if (c == 0) {
        const float per_sample = acc[k * 64 + 0] / cnt;
        const float commit = acc[k * 64 + 1] / cnt;
        const float pen = (per_sample - ec) * (1.0f / 100.0f);
        outL[k] = pen * 0.1f + commit * 0.2f;
    }
}

extern "C" void kernel_launch(void* const* d_in, const int* in_sizes, int n_in,
                              void* d_out, int out_size, void* d_ws, size_t ws_size,
                              hipStream_t stream) {
    (void)in_sizes; (void)n_in; (void)out_size; (void)ws_size;
    const float* f = (const float*)d_in[0];
    float* outQ = (float*)d_out;                        // N_ELEM floats
    float* outBits = outQ + N_ELEM;                     // BITS_ELEM floats (0.0/1.0)
    float* outL = outBits + BITS_ELEM;                  // 14 floats

    float* partial = (float*)d_ws;                      // 14*34*2048 floats (~3.9MB)
    float* acc = partial + (size_t)NLEVEL * 34 * PARTW; // 14*64 floats
    float* F128 = acc + NLEVEL * 64;                    // B*128*C floats (0.5MB)
    unsigned int* pkG = (unsigned int*)(F128 + (size_t)B_DIM * 128 * C_DIM); // B*8192 words

    init_kernel<<<B_DIM * 128, 256, 0, stream>>>(f, F128);
    fused_small_kernel<<<B_DIM, 1024, 0, stream>>>(F128, outBits, pkG, partial);
    chunk_kernel<<<B_DIM * 32, 256, 0, stream>>>(f, outBits, pkG, partial);
    final_kernel<<<B_DIM * 32, 256, 0, stream>>>(f, outQ, outBits, pkG, partial);
    reduce_partials<<<NLEVEL * 34, 64, 0, stream>>>(partial, acc);
    finalize_kernel<<<1, 512, 0, stream>>>(acc, outL);
}

// Round 8
// 171.141 us; speedup vs baseline: 1.7388x; 1.0063x over previous
//
#include <hip/hip_runtime.h>

#define B_DIM 32
#define T_DIM 8192
#define C_DIM 32
#define N_ELEM (B_DIM * T_DIM * C_DIM)      /* 8388608 */
#define SUM_PT 16383
#define BITS_ELEM (B_DIM * SUM_PT * C_DIM)  /* 16776192 */
#define NLEVEL 14
#define PARTW 2048
#define QSCALE 0.17677669529663687f         /* 1/sqrt(32) */
#define ALPHA  70.710678118654755f          /* 4*INV_TEMP/sqrt(32) */

#define OWN 128                              /* 4096-res rows owned per chunk block */
#define HALO 16
#define MAXL (OWN + 2 * HALO)                /* 160 */

__device__ __forceinline__ float entf(float x) { return -(x * __logf(x + 1e-8f)); }
__device__ __forceinline__ float qval(float bit) { return bit * (2.0f * QSCALE) - QSCALE; }

// interp of level-j quant at (possibly half-integer) T-position tpos, packed bit c.
__device__ __forceinline__ float interp_pk(const unsigned int* __restrict__ pkbase,
                                           int ptj, float tpos, int c) {
    const float a = (float)ptj * (1.0f / (float)T_DIM);
    float pos = (tpos + 0.5f) * a - 0.5f;
    pos = fminf(fmaxf(pos, 0.0f), (float)(ptj - 1));
    const int lo = (int)pos;
    const int hi = min(lo + 1, ptj - 1);
    const float w = pos - (float)lo;
    const float b0 = (float)((pkbase[lo] >> c) & 1u);
    const float b1 = (float)((pkbase[hi] >> c) & 1u);
    return ((b0 * (1.0f - w) + b1 * w) * 2.0f - 1.0f) * QSCALE;
}

// pooled-to-4096 correction of level k via midpoint identity, local packed window.
__device__ __forceinline__ float corr_mid_local(const unsigned int* __restrict__ bl,
                                                int ptk, int row, int c, int p0, int pN) {
    const float a = (float)ptk * (1.0f / (float)T_DIM);
    float pos = (float)(2 * row + 1) * a - 0.5f;
    pos = fminf(fmaxf(pos, 0.0f), (float)(ptk - 1));
    const int lo = (int)pos;
    const int hi = min(lo + 1, ptk - 1);
    const float w = pos - (float)lo;
    const int lol = min(max(lo - p0, 0), pN - 1);   // clamp only hits don't-care halo
    const int hil = min(max(hi - p0, 0), pN - 1);
    const float b0 = (float)((bl[lol] >> c) & 1u);
    const float b1 = (float)((bl[hil] >> c) & 1u);
    return ((b0 * (1.0f - w) + b1 * w) * 2.0f - 1.0f) * QSCALE;
}

// Closed-form sum over t in [m*64,(m+1)*64) of float-bits interp, ptj <= 64.
__device__ float pooled_up_sum64(const float* base, int ptj, int m) {
    const int W = 64;
    const float a = (float)ptj * (1.0f / (float)T_DIM);
    const float p0 = ((float)(m * W) + 0.5f) * a - 0.5f;
    const float pmax = (float)(ptj - 1);
    float sum = 0.0f;
    int iL = 0;
    if (p0 < 0.0f) { iL = (int)ceilf(-p0 / a); if (iL > W) iL = W; }
    int iH = W - 1;
    if (p0 + (float)(W - 1) * a > pmax) {
        iH = (int)floorf((pmax - p0) / a);
        if (iH > W - 1) iH = W - 1;
        if (iH < -1) iH = -1;
    }
    if (iL > 0) sum += (float)iL * qval(base[0]);
    if (iH < W - 1) sum += (float)(W - 1 - iH) * qval(base[(size_t)(ptj - 1) * C_DIM]);
    if (iH >= iL) {
        const float pL = p0 + (float)iL * a;
        int l0 = (int)pL;
        if (l0 > ptj - 1) l0 = ptj - 1;
        const int is = (int)ceilf(((float)(l0 + 1) - p0) / a);
        const int endA = min(is - 1, iH);
        if (endA >= iL) {
            const int nA = endA - iL + 1;
            const float sI = 0.5f * (float)(iL + endA) * (float)nA;
            const float SA = (float)nA * (p0 - (float)l0) + a * sI;
            const float q0 = qval(base[(size_t)l0 * C_DIM]);
            const float q1 = qval(base[(size_t)min(l0 + 1, ptj - 1) * C_DIM]);
            sum += (float)nA * q0 + SA * (q1 - q0);
        }
        const int begB = max(is, iL);
        if (begB <= iH) {
            const int nB = iH - begB + 1;
            const float sI = 0.5f * (float)(begB + iH) * (float)nB;
            const float SB = (float)nB * (p0 - (float)(l0 + 1)) + a * sI;
            const float q1 = qval(base[(size_t)min(l0 + 1, ptj - 1) * C_DIM]);
            const float q2 = qval(base[(size_t)min(l0 + 2, ptj - 1) * C_DIM]);
            sum += (float)nB * q1 + SB * (q2 - q1);
        }
    }
    return sum;
}

template <int NT>
__device__ __forceinline__ void write_partials(float eAcc, float cAcc, float pAcc,
                                               float* partial, int level, int col) {
    __shared__ float sP[NT];
    __shared__ float sEC[NT / 16];
    __syncthreads();
    const int grp = threadIdx.x >> 5, c = threadIdx.x & 31;
    float eg = eAcc, cg = cAcc;
#pragma unroll
    for (int m = 16; m >= 1; m >>= 1) { eg += __shfl_xor(eg, m, 32); cg += __shfl_xor(cg, m, 32); }
    if (c == 0) { sEC[grp * 2] = eg; sEC[grp * 2 + 1] = cg; }
    sP[threadIdx.x] = pAcc;
    __syncthreads();
    float* base = partial + (size_t)level * 34 * PARTW;
    if (threadIdx.x < 32) {
        float ps = 0.f;
#pragma unroll
        for (int r = 0; r < NT / 32; ++r) ps += sP[threadIdx.x + r * 32];
        base[(size_t)(2 + threadIdx.x) * PARTW + col] = ps;
    }
    if (threadIdx.x == 0) {
        float se = 0.f, sc = 0.f;
#pragma unroll
        for (int g = 0; g < NT / 32; ++g) { se += sEC[2 * g]; sc += sEC[2 * g + 1]; }
        base[0 * PARTW + col] = se;
        base[(size_t)1 * PARTW + col] = sc;
    }
}

__device__ __forceinline__ float bsq_eval(float v, float& bit, float& pA, float& eA, float& cA) {
    float sq = v * v;
#pragma unroll
    for (int m = 16; m >= 1; m >>= 1) sq += __shfl_xor(sq, m, 32);
    const float z = v / fmaxf(sqrtf(sq), 1e-12f);
    bit = (z > 0.f) ? 1.0f : 0.0f;
    const float zh = (z > 0.f) ? QSCALE : -QSCALE;
    const float d = zh - z;
    cA += d * d;
    const float p = 1.0f / (1.0f + __expf(ALPHA * z));
    pA += p;
    eA += entf(p) + entf(1.0f - p);
    return zh;
}

// ---------------------------------------------------------------------------
// init: F128[b,m,c] = mean of 64 f rows. Grid B*128.
// ---------------------------------------------------------------------------
__global__ void init_kernel(const float* __restrict__ f, float* __restrict__ F128) {
    const int b = blockIdx.x >> 7, m = blockIdx.x & 127;
    const int c = threadIdx.x & 31, grp = threadIdx.x >> 5;
    const float* fb = f + ((size_t)b * T_DIM + m * 64 + grp * 8) * C_DIM + c;
    float s = 0.f;
#pragma unroll
    for (int i = 0; i < 8; ++i) s += fb[i * C_DIM];
    __shared__ float red[8][32];
    red[grp][c] = s;
    __syncthreads();
    if (grp == 0) {
        float t = red[0][c] + red[1][c] + red[2][c] + red[3][c]
                + red[4][c] + red[5][c] + red[6][c] + red[7][c];
        F128[((size_t)b * 128 + m) * C_DIM + c] = t * (1.0f / 64.0f);
    }
}

// ---------------------------------------------------------------------------
// Levels 0..7: one 1024-thread block per b; P128 in LDS; closed-form corr.
// ---------------------------------------------------------------------------
__global__ __launch_bounds__(1024) void fused_small_kernel(const float* __restrict__ F128,
                                                           float* __restrict__ bits,
                                                           unsigned int* __restrict__ pkG,
                                                           float* __restrict__ partial) {
    const int b = blockIdx.x;
    __shared__ float P[128 * 32];
    __shared__ float qh[127 * 32];
    const int c = threadIdx.x & 31, grp = threadIdx.x >> 5;
    for (int i = threadIdx.x; i < 128 * 32; i += 1024) P[i] = F128[(size_t)b * 128 * 32 + i];
    __syncthreads();
    for (int k = 0; k < 8; ++k) {
        const int pt = 1 << k, W2 = 128 >> k;
        float pAcc = 0.f, eAcc = 0.f, cAcc = 0.f;
        for (int o = grp; o < pt; o += 32) {
            float v = 0.f;
            for (int i = 0; i < W2; ++i) v += P[(o * W2 + i) * 32 + c];
            v *= (1.0f / (float)W2);
            float bit;
            bsq_eval(v, bit, pAcc, eAcc, cAcc);
            bits[((size_t)b * SUM_PT + (pt - 1) + o) * C_DIM + c] = bit;
            const unsigned long long bal = __ballot(bit > 0.5f);
            if (c == 0)
                pkG[(size_t)b * 8192 + (pt - 1) + o] =
                    (threadIdx.x & 32) ? (unsigned)(bal >> 32) : (unsigned)bal;
            if (k < 7) qh[((pt - 1) + o) * 32 + c] = bit;
        }
        write_partials<1024>(eAcc, cAcc, pAcc, partial, k, b);
        if (k < 7) {
            __syncthreads();
            for (int m = grp; m < 128; m += 32)
                P[m * 32 + c] -= pooled_up_sum64(&qh[(pt - 1) * 32 + c], 1 << k, m) * (1.0f / 64.0f);
            __syncthreads();
        }
    }
}

// ---------------------------------------------------------------------------
// Levels 8..12 chunk (512 threads = 16 channel-groups): pool f 2:1 on load;
// segment-linear j<=7 correction; per-level pool->BSQ->mid-interp correct.
// ---------------------------------------------------------------------------
__global__ __launch_bounds__(512) void chunk_kernel(const float* __restrict__ f,
                                                    float* __restrict__ bits,
                                                    unsigned int* __restrict__ pkG,
                                                    float* __restrict__ partial) {
    const int b = blockIdx.x >> 5;
    const int chunk = blockIdx.x & 31;
    const int r0 = chunk * OWN, r1 = r0 + OWN;
    const int L0 = max(0, r0 - HALO);
    const int L1 = min(4096, r1 + HALO);
    const int nL = L1 - L0;
    const int nSeg = nL >> 4;
    __shared__ float Rl[MAXL * 32];
    __shared__ unsigned int bitsL[310];
    __shared__ unsigned int pk07[255];
    __shared__ float segA[10][32], segB[10][32];
    const int c = threadIdx.x & 31, grp = threadIdx.x >> 5;   // 16 groups

    const float* fb = f + ((size_t)b * T_DIM + (size_t)L0 * 2) * C_DIM;
    for (int i = threadIdx.x; i < nL * 8; i += 512) {
        const int row = i >> 3, c4 = i & 7;
        const float4 v0 = *(const float4*)(fb + (size_t)(2 * row) * 32 + c4 * 4);
        const float4 v1 = *(const float4*)(fb + (size_t)(2 * row + 1) * 32 + c4 * 4);
        float4 o;
        o.x = 0.5f * (v0.x + v1.x); o.y = 0.5f * (v0.y + v1.y);
        o.z = 0.5f * (v0.z + v1.z); o.w = 0.5f * (v0.w + v1.w);
        *(float4*)(Rl + row * 32 + c4 * 4) = o;
    }
    for (int i = threadIdx.x; i < 255; i += 512) pk07[i] = pkG[(size_t)b * 8192 + i];
    __syncthreads();

    // j<=7 batch correction: 2 mid-evals per 16-row segment, linear apply.
    for (int w = threadIdx.x; w < nSeg * 32; w += 512) {
        const int s = w >> 5, cc = w & 31;
        const int rg = L0 + s * 16;
        float c0 = 0.f, c1 = 0.f;
#pragma unroll
        for (int j = 0; j < 8; ++j) {
            const int ptj = 1 << j;
            c0 += interp_pk(pk07 + (ptj - 1), ptj, (float)(2 * rg) + 0.5f, cc);
            c1 += interp_pk(pk07 + (ptj - 1), ptj, (float)(2 * rg + 2) + 0.5f, cc);
        }
        segA[s][cc] = c0;
        segB[s][cc] = c1 - c0;
    }
    __syncthreads();
    for (int rl = grp; rl < nL; rl += 16) {
        const int s = rl >> 4;
        Rl[rl * 32 + c] -= fmaf((float)(rl & 15), segB[s][c], segA[s][c]);
    }
    __syncthreads();

    const int offs[5] = {0, 10, 30, 70, 150};
    for (int k = 8; k <= 12; ++k) {
        const int F = 4096 >> k;
        const int ptk = 1 << k;
        const int p0 = L0 / F, pN = nL / F;
        const int own0 = r0 / F, own1 = r1 / F;
        const int off = offs[k - 8];
        float pAcc = 0.f, eAcc = 0.f, cAcc = 0.f;
        for (int pl = grp; pl < pN; pl += 16) {
            float v = 0.f;
            for (int r = 0; r < F; ++r) v += Rl[(pl * F + r) * 32 + c];
            v *= (1.0f / (float)F);
            float sq = v * v;
#pragma unroll
            for (int m = 16; m >= 1; m >>= 1) sq += __shfl_xor(sq, m, 32);
            const float z = v / fmaxf(sqrtf(sq), 1e-12f);
            const unsigned long long bal = __ballot(z > 0.f);
            const unsigned int word = (threadIdx.x & 32) ? (unsigned)(bal >> 32) : (unsigned)bal;
            if (c == 0) bitsL[off + pl] = word;
            const int mg = p0 + pl;
            if (mg >= own0 && mg < own1) {
                bits[((size_t)b * SUM_PT + (ptk - 1) + mg) * C_DIM + c] = (z > 0.f) ? 1.f : 0.f;
                if (c == 0) pkG[(size_t)b * 8192 + (ptk - 1) + mg] = word;
                const float zh = (z > 0.f) ? QSCALE : -QSCALE;
                const float d = zh - z;
                cAcc += d * d;
                const float p = 1.0f / (1.0f + __expf(ALPHA * z));
                pAcc += p;
                eAcc += entf(p) + entf(1.0f - p);
            }
        }
        write_partials<512>(eAcc, cAcc, pAcc, partial, k, blockIdx.x);
        __syncthreads();
        if (k < 12) {
            for (int rl = grp; rl < nL; rl += 16)
                Rl[rl * 32 + c] -= corr_mid_local(bitsL + off, ptk, L0 + rl, c, p0, pN);
            __syncthreads();
        }
    }
}

// ---------------------------------------------------------------------------
// Level 13 (512 threads): segment-linear j<=8 + direct j=9..12 from windowed
// packed bits; out = up + zhat; bits13; loss partials.
// ---------------------------------------------------------------------------
__global__ __launch_bounds__(512) void final_kernel(const float* __restrict__ f,
                                                    float* __restrict__ outQ,
                                                    float* __restrict__ bits,
                                                    const unsigned int* __restrict__ pkG,
                                                    float* __restrict__ partial) {
    const int b = blockIdx.x >> 5;
    const int sub = blockIdx.x & 31;
    const int t0 = sub * 256;
    __shared__ unsigned int pkW[764];
    __shared__ float segA[16][32], segB[16][32];
    const int c = threadIdx.x & 31, grp = threadIdx.x >> 5;   // 16 groups
    const unsigned int* pgb = pkG + (size_t)b * 8192;
    for (int i = threadIdx.x; i < 511; i += 512) pkW[i] = pgb[i];
    int woff[4], wbase[4];
    int o = 511;
#pragma unroll
    for (int j = 9; j <= 12; ++j) {
        const int ptj = 1 << j;
        const int w0 = max(0, ((t0 * ptj) >> 13) - 1);
        const int w1 = min(ptj - 1, (((t0 + 256) * ptj) >> 13) + 1);
        const int cnt = w1 - w0 + 1;
        for (int i = threadIdx.x; i < cnt; i += 512) pkW[o + i] = pgb[(ptj - 1) + w0 + i];
        woff[j - 9] = o;
        wbase[j - 9] = w0;
        o += cnt;
    }
    __syncthreads();
    for (int w = threadIdx.x; w < 512; w += 512) {
        const int s = w >> 5, cc = w & 31;
        const int tA = t0 + s * 16;
        float c0 = 0.f, c1 = 0.f;
#pragma unroll
        for (int j = 0; j <= 8; ++j) {
            const int ptj = 1 << j;
            c0 += interp_pk(pkW + (ptj - 1), ptj, (float)tA, cc);
            c1 += interp_pk(pkW + (ptj - 1), ptj, (float)(tA + 1), cc);
        }
        segA[s][cc] = c0;
        segB[s][cc] = c1 - c0;
    }
    __syncthreads();
    float pAcc = 0.f, eAcc = 0.f, cAcc = 0.f;
    for (int tt = grp; tt < 256; tt += 16) {
        const int t = t0 + tt;
        float up = fmaf((float)(tt & 15), segB[tt >> 4][c], segA[tt >> 4][c]);
#pragma unroll
        for (int j = 9; j <= 12; ++j) {
            const int ptj = 1 << j;
            const float a = (float)ptj * (1.0f / (float)T_DIM);
            float pos = ((float)t + 0.5f) * a - 0.5f;
            pos = fminf(fmaxf(pos, 0.0f), (float)(ptj - 1));
            const int lo = (int)pos;
            const int hi = min(lo + 1, ptj - 1);
            const float w = pos - (float)lo;
            const unsigned int* base = pkW + (woff[j - 9] - wbase[j - 9]);
            const float b0 = (float)((base[lo] >> c) & 1u);
            const float b1 = (float)((base[hi] >> c) & 1u);
            up += ((b0 * (1.0f - w) + b1 * w) * 2.0f - 1.0f) * QSCALE;
        }
        const size_t idx = ((size_t)b * T_DIM + t) * C_DIM + c;
        const float v = f[idx] - up;
        float bit;
        const float zh = bsq_eval(v, bit, pAcc, eAcc, cAcc);
        bits[((size_t)b * SUM_PT + (T_DIM - 1) + t) * C_DIM + c] = bit;
        outQ[idx] = up + zh;
    }
    write_partials<512>(eAcc, cAcc, pAcc, partial, 13, blockIdx.x);
}

// ---------------------------------------------------------------------------
__global__ void reduce_partials(const float* __restrict__ partial, float* __restrict__ acc) {
    const int level = blockIdx.x / 34;
    const int comp = blockIdx.x % 34;
    const int nblk = (level < 8) ? 32 : 1024;
    const float* s = partial + ((size_t)level * 34 + comp) * PARTW;
    float v = 0.f;
    for (int i = threadIdx.x; i < nblk; i += 64) v += s[i];
#pragma unroll
    for (int m = 32; m >= 1; m >>= 1) v += __shfl_xor(v, m, 64);
    if (threadIdx.x == 0) acc[level * 64 + comp] = v;
}

__global__ void finalize_kernel(const float* __restrict__ acc, float* __restrict__ outL) {
    const int k = threadIdx.x >> 5;
    const int c = threadIdx.x & 31;
    if (k >= NLEVEL) return;
    const float cnt = (float)(B_DIM << k);
    const float avg_p = acc[k * 64 + 2 + c] / cnt;
    float ec = entf(avg_p) + entf(1.0f - avg_p);
#pragma unroll
    for (int m = 16; m >= 1; m >>= 1) ec += __shfl_xor(ec, m, 32);
    if (c == 0) {
        const float per_sample = acc[k * 64 + 0] / cnt;
        const float commit = acc[k * 64 + 1] / cnt;
        const float pen = (per_sample - ec) * (1.0f / 100.0f);
        outL[k] = pen * 0.1f + commit * 0.2f;
    }
}

extern "C" void kernel_launch(void* const* d_in, const int* in_sizes, int n_in,
                              void* d_out, int out_size, void* d_ws, size_t ws_size,
                              hipStream_t stream) {
    (void)in_sizes; (void)n_in; (void)out_size; (void)ws_size;
    const float* f = (const float*)d_in[0];
    float* outQ = (float*)d_out;                        // N_ELEM floats
    float* outBits = outQ + N_ELEM;                     // BITS_ELEM floats (0.0/1.0)
    float* outL = outBits + BITS_ELEM;                  // 14 floats

    float* partial = (float*)d_ws;                      // 14*34*2048 floats (~3.9MB)
    float* acc = partial + (size_t)NLEVEL * 34 * PARTW; // 14*64 floats
    float* F128 = acc + NLEVEL * 64;                    // B*128*C floats (0.5MB)
    unsigned int* pkG = (unsigned int*)(F128 + (size_t)B_DIM * 128 * C_DIM); // B*8192 words

    init_kernel<<<B_DIM * 128, 256, 0, stream>>>(f, F128);
    fused_small_kernel<<<B_DIM, 1024, 0, stream>>>(F128, outBits, pkG, partial);
    chunk_kernel<<<B_DIM * 32, 512, 0, stream>>>(f, outBits, pkG, partial);
    final_kernel<<<B_DIM * 32, 512, 0, stream>>>(f, outQ, outBits, pkG, partial);
    reduce_partials<<<NLEVEL * 34, 64, 0, stream>>>(partial, acc);
    finalize_kernel<<<1, 512, 0, stream>>>(acc, outL);
}